// Round 16
// baseline (216.986 us; speedup 1.0000x reference)
//
#include <hip/hip_runtime.h>
#include <math.h>

#define D_MODEL 1024
#define N_HEAD  16
#define DH      64
#define SEQ     2048
#define BATCH   4
#define BH      (BATCH*N_HEAD)   // 64
#define MROWS   (BATCH*SEQ)      // 8192

typedef __attribute__((ext_vector_type(8)))  short          s16x8;
typedef __attribute__((ext_vector_type(8)))  unsigned short u16x8;
typedef __attribute__((ext_vector_type(4)))  unsigned short u16x4;
typedef __attribute__((ext_vector_type(4)))  float          f32x4;
typedef __attribute__((ext_vector_type(16))) float          f32x16;
typedef __attribute__((ext_vector_type(4)))  unsigned int   u32x4;

#define QSCALE 0.18033688f   // 0.125 * log2(e)

typedef const __attribute__((address_space(1))) unsigned int gu32;
typedef __attribute__((address_space(3))) unsigned int lu32;
#define GLOAD_LDS16(g, l) __builtin_amdgcn_global_load_lds((gu32*)(g), (lu32*)(l), 16, 0, 0)

__device__ __forceinline__ unsigned short f2bf(float x) {
    unsigned int u = __float_as_uint(x);
    u += 0x7FFFu + ((u >> 16) & 1u);      // round-to-nearest-even
    return (unsigned short)(u >> 16);
}

__device__ __forceinline__ unsigned int cvtpk_bf16(float lo, float hi) {
    unsigned int r;
    asm("v_cvt_pk_bf16_f32 %0, %1, %2" : "=v"(r) : "v"(lo), "v"(hi));
    return r;
}

__device__ __forceinline__ float exp2_asm(float x) {
    float r;
    asm("v_exp_f32 %0, %1" : "=v"(r) : "v"(x));
    return r;
}

__device__ __forceinline__ float max3f(float a, float b, float c) {
    float r;
    asm("v_max3_f32 %0, %1, %2, %3" : "=v"(r) : "v"(a), "v"(b), "v"(c));
    return r;
}

// ---------------------------------------------------------------------------
// all four weight matrices fp32 -> bf16 in one dispatch. grid (512, 4).
// ---------------------------------------------------------------------------
__global__ __launch_bounds__(256) void conv_w4(const float* __restrict__ w0,
                                               const float* __restrict__ w1,
                                               const float* __restrict__ w2,
                                               const float* __restrict__ w3,
                                               unsigned short* __restrict__ o0,
                                               unsigned short* __restrict__ o1,
                                               unsigned short* __restrict__ o2,
                                               unsigned short* __restrict__ o3)
{
    const float* w; unsigned short* o;
    switch (blockIdx.y) {
        case 0:  w = w0; o = o0; break;
        case 1:  w = w1; o = o1; break;
        case 2:  w = w2; o = o2; break;
        default: w = w3; o = o3; break;
    }
    int i = blockIdx.x * 256 + threadIdx.x;
    const float4* p = (const float4*)w + (size_t)i * 2;
    float4 a = p[0], b = p[1];
    u16x8 v;
    v[0] = f2bf(a.x); v[1] = f2bf(a.y); v[2] = f2bf(a.z); v[3] = f2bf(a.w);
    v[4] = f2bf(b.x); v[5] = f2bf(b.y); v[6] = f2bf(b.z); v[7] = f2bf(b.w);
    *((u16x8*)o + i) = v;
}

// ---------------------------------------------------------------------------
// C[M=8192][N=1024] = A[M][1024] @ W(bf16)[N=1024][1024]^T + bias, then *oscale
// 128x128 tile, BK=64, grid (64,8)=512 blocks.
// DOUBLE-BUFFERED stage-ahead loop (m97/flash pattern): step k+1's B DMA +
// A ds_writes are issued into buf^1 BEFORE computing step k from buf, with
// ONE barrier per step — the DMA flies under the 32-MFMA compute phase
// instead of being drained immediately (R15's 2-barrier loop exposed the
// full L2 latency per step). Buffer-swap safety: buf^1 at step k was last
// READ at step k-1, whose end-of-step barrier precedes these writes.
// B via global_load_lds w/ pre-swizzled source; A reg-staged (cvtpk if AF32).
// ---------------------------------------------------------------------------
template<int MODE, bool AF32>
__global__ __launch_bounds__(256) void gemm_bt(const void* __restrict__ Av,
                                               const unsigned short* __restrict__ W,
                                               const float* __restrict__ bias,
                                               unsigned short* __restrict__ outb,
                                               float* __restrict__ outf,
                                               float oscale)
{
    __shared__ short As[2][128 * 64];   // 2 x 16KB, XOR-swizzled 16B groups
    __shared__ short Bs[2][128 * 64];   // 2 x 16KB
    const int tid = threadIdx.x;
    const int w = tid >> 6, l = tid & 63;
    const int lr = l & 15, lg = l >> 4;
    const int wm = w >> 1, wn = w & 1;
    const int r0 = blockIdx.x * 128, c0 = blockIdx.y * 128;
    const int srow = tid >> 3;   // 0..31
    const int sc8  = tid & 7;    // 0..7

    f32x4 zz = {0.f, 0.f, 0.f, 0.f};
    f32x4 acc[4][4];
    #pragma unroll
    for (int i = 0; i < 4; ++i)
        #pragma unroll
        for (int j = 0; j < 4; ++j) acc[i][j] = zz;

    const unsigned short* Ab = (const unsigned short*)Av;
    const float*          Af = (const float*)Av;

    // per-lane pre-swizzled B source offsets (bytes), one per 8-row DMA
    const int lrow8 = l >> 3;      // 0..7
    const int lslot = l & 7;
    size_t bsrc[4];
    #pragma unroll
    for (int p = 0; p < 4; ++p)
        bsrc[p] = ((size_t)(c0 + w * 32 + p * 8 + lrow8) * 1024 + (size_t)((lslot ^ lrow8) * 8)) * 2;

    u16x8 ar[4];
    float4 arf[4][2];

    // ---- load A regs for step 0
    #pragma unroll
    for (int p = 0; p < 4; ++p) {
        int row = p * 32 + srow;
        if (AF32) {
            arf[p][0] = *(const float4*)(Af + (size_t)(r0 + row) * 1024 + sc8 * 8);
            arf[p][1] = *(const float4*)(Af + (size_t)(r0 + row) * 1024 + sc8 * 8 + 4);
        } else {
            ar[p] = *(const u16x8*)(Ab + (size_t)(r0 + row) * 1024 + sc8 * 8);
        }
    }
    // ---- stage step 0 into buf 0
    #pragma unroll
    for (int p = 0; p < 4; ++p)
        GLOAD_LDS16((const char*)W + bsrc[p], &Bs[0][(w * 32 + p * 8) * 64]);
    #pragma unroll
    for (int p = 0; p < 4; ++p) {
        int row = p * 32 + srow;
        if (AF32) {
            u32x4 wd;
            wd[0] = cvtpk_bf16(arf[p][0].x, arf[p][0].y);
            wd[1] = cvtpk_bf16(arf[p][0].z, arf[p][0].w);
            wd[2] = cvtpk_bf16(arf[p][1].x, arf[p][1].y);
            wd[3] = cvtpk_bf16(arf[p][1].z, arf[p][1].w);
            *(u16x8*)&As[0][row * 64 + ((sc8 ^ (row & 7)) * 8)] = __builtin_bit_cast(u16x8, wd);
        } else {
            *(u16x8*)&As[0][row * 64 + ((sc8 ^ (row & 7)) * 8)] = ar[p];
        }
    }
    // ---- prefetch A regs for step 1
    #pragma unroll
    for (int p = 0; p < 4; ++p) {
        int row = p * 32 + srow;
        if (AF32) {
            arf[p][0] = *(const float4*)(Af + (size_t)(r0 + row) * 1024 + 64 + sc8 * 8);
            arf[p][1] = *(const float4*)(Af + (size_t)(r0 + row) * 1024 + 64 + sc8 * 8 + 4);
        } else {
            ar[p] = *(const u16x8*)(Ab + (size_t)(r0 + row) * 1024 + 64 + sc8 * 8);
        }
    }
    __syncthreads();   // step-0 staging complete

    int buf = 0;
    for (int ks = 0; ks < 16; ++ks) {
        // ---- stage step ks+1 into buf^1 (DMA overlaps the compute below)
        if (ks < 15) {
            #pragma unroll
            for (int p = 0; p < 4; ++p)
                GLOAD_LDS16((const char*)W + bsrc[p] + (size_t)(ks + 1) * 128,
                            &Bs[buf ^ 1][(w * 32 + p * 8) * 64]);
            #pragma unroll
            for (int p = 0; p < 4; ++p) {
                int row = p * 32 + srow;
                if (AF32) {
                    u32x4 wd;
                    wd[0] = cvtpk_bf16(arf[p][0].x, arf[p][0].y);
                    wd[1] = cvtpk_bf16(arf[p][0].z, arf[p][0].w);
                    wd[2] = cvtpk_bf16(arf[p][1].x, arf[p][1].y);
                    wd[3] = cvtpk_bf16(arf[p][1].z, arf[p][1].w);
                    *(u16x8*)&As[buf ^ 1][row * 64 + ((sc8 ^ (row & 7)) * 8)] = __builtin_bit_cast(u16x8, wd);
                } else {
                    *(u16x8*)&As[buf ^ 1][row * 64 + ((sc8 ^ (row & 7)) * 8)] = ar[p];
                }
            }
            if (ks < 14) {
                int k0 = (ks + 2) * 64;
                #pragma unroll
                for (int p = 0; p < 4; ++p) {
                    int row = p * 32 + srow;
                    if (AF32) {
                        arf[p][0] = *(const float4*)(Af + (size_t)(r0 + row) * 1024 + k0 + sc8 * 8);
                        arf[p][1] = *(const float4*)(Af + (size_t)(r0 + row) * 1024 + k0 + sc8 * 8 + 4);
                    } else {
                        ar[p] = *(const u16x8*)(Ab + (size_t)(r0 + row) * 1024 + k0 + sc8 * 8);
                    }
                }
            }
        }
        // ---- compute step ks from buf
        #pragma unroll
        for (int t = 0; t < 2; ++t) {
            const int k8 = lg + 4 * t;
            s16x8 af[4], bw[4];
            #pragma unroll
            for (int i = 0; i < 4; ++i) {
                int rowa = wm * 64 + i * 16 + lr;
                af[i] = *(const s16x8*)&As[buf][rowa * 64 + ((k8 ^ (rowa & 7)) * 8)];
                int rowb = wn * 64 + i * 16 + lr;
                bw[i] = *(const s16x8*)&Bs[buf][rowb * 64 + ((k8 ^ (rowb & 7)) * 8)];
            }
            #pragma unroll
            for (int i = 0; i < 4; ++i)
                #pragma unroll
                for (int j = 0; j < 4; ++j)
                    acc[i][j] = __builtin_amdgcn_mfma_f32_16x16x32_bf16(af[i], bw[j], acc[i][j], 0, 0, 0);
        }
        if (ks < 15) {
            __syncthreads();   // next buf fully staged (DMA landed during compute)
            buf ^= 1;
        }
    }

    #pragma unroll
    for (int i = 0; i < 4; ++i) {
        #pragma unroll
        for (int j = 0; j < 4; ++j) {
            const int colb = c0 + wn * 64 + j * 16 + lr;
            const float bv = bias[colb];
            if (MODE == 2) {
                const int row = r0 + wm * 64 + i * 16 + lg * 4;
                const int b = row >> 11, s = row & 2047;
                const int h = colb >> 6, d = colb & 63;
                u16x4 pv;
                pv[0] = f2bf((acc[i][j][0] + bv) * oscale);
                pv[1] = f2bf((acc[i][j][1] + bv) * oscale);
                pv[2] = f2bf((acc[i][j][2] + bv) * oscale);
                pv[3] = f2bf((acc[i][j][3] + bv) * oscale);
                *(u16x4*)(outb + ((size_t)(b * N_HEAD + h) * DH + d) * SEQ + s) = pv;
            } else {
                #pragma unroll
                for (int rg = 0; rg < 4; ++rg) {
                    const int row = r0 + wm * 64 + i * 16 + lg * 4 + rg;
                    const float v = acc[i][j][rg] + bv;
                    if (MODE == 0) {
                        outf[(size_t)row * D_MODEL + colb] = v;
                    } else {
                        const int b = row >> 11, s = row & 2047;
                        const int h = colb >> 6, d = colb & 63;
                        outb[((size_t)(b * N_HEAD + h) * SEQ + s) * DH + d] = f2bf(v * oscale);
                    }
                }
            }
        }
    }
}

// ---------------------------------------------------------------------------
// Swapped-operand MFMA flash attention (32x32x16), log2-domain, dbuf LDS.
// R12 version verbatim (measured 96.4us, FETCH 27.7MB). R13's max-free +
// ZERO-reg variant raised occupancy 33->43% and broke the fragile L2
// lockstep of same-head blocks (FETCH 27.7->711MB, 26x): per-XCD K/V
// working set is exactly 4MB=L2, so pacing changes cause thrash. Do not
// alter this kernel's timing/occupancy without checking FETCH_SIZE.
// ---------------------------------------------------------------------------
__global__ __launch_bounds__(256, 4) void flash_attn_mfma32(const unsigned short* __restrict__ qb,
                                                            const unsigned short* __restrict__ kb,
                                                            const unsigned short* __restrict__ vtb,
                                                            unsigned short* __restrict__ aob)
{
    __shared__ u16x8 Kt[2][512];   // 16KB double-buffered
    __shared__ u16x8 Vt[2][512];   // 16KB

    const int tid = threadIdx.x;
    const int w = tid >> 6, l = tid & 63;
    const int q32 = l & 31;
    const int h = l >> 5;

    // XCD-aware decode: all 16 q-tiles of a (b,h) land on one XCD
    const int wg   = blockIdx.x;          // 0..1023
    const int xcd  = wg & 7;
    const int slot = wg >> 3;             // 0..127
    const int bh   = xcd * 8 + (slot >> 4);
    const int qt   = slot & 15;

    const unsigned short* qh = qb + (size_t)bh * SEQ * DH;
    const unsigned short* kh = kb + (size_t)bh * SEQ * DH;
    const unsigned short* vh = vtb + (size_t)bh * DH * SEQ;

    const int qrow = qt * 128 + w * 32 + q32;

    s16x8 qf[4];
    #pragma unroll
    for (int ks = 0; ks < 4; ++ks)
        qf[ks] = *(const s16x8*)(qh + (size_t)qrow * DH + ks * 16 + h * 8);

    f32x16 O[2];
    #pragma unroll
    for (int r = 0; r < 16; ++r) { O[0][r] = 0.f; O[1][r] = 0.f; }
    float m = 0.f, lsum = 0.f;   // log2-domain; P bounded by 2^8 via defer check

    const int srow = tid >> 3;   // 0..31
    const int sc8  = tid & 7;

    u16x8 kreg[2], vreg[2];
    #pragma unroll
    for (int p = 0; p < 2; ++p) {
        int rr = p * 32 + srow;
        kreg[p] = *(const u16x8*)(kh + (size_t)rr * DH + sc8 * 8);
        vreg[p] = *(const u16x8*)(vh + (size_t)rr * SEQ + sc8 * 8);
    }
    #pragma unroll
    for (int p = 0; p < 2; ++p) {
        int rr = p * 32 + srow;
        Kt[0][sc8 * 64 + (rr ^ sc8)] = kreg[p];
        Vt[0][sc8 * 64 + (rr ^ sc8)] = vreg[p];
    }
    __syncthreads();

    int buf = 0;
    for (int kv = 0; kv < SEQ / 64; ++kv) {
        // issue next tile's global loads early (latency hides under compute)
        if (kv < SEQ / 64 - 1) {
            const int s0 = (kv + 1) * 64;
            #pragma unroll
            for (int p = 0; p < 2; ++p) {
                int rr = p * 32 + srow;
                kreg[p] = *(const u16x8*)(kh + (size_t)(s0 + rr) * DH + sc8 * 8);
                vreg[p] = *(const u16x8*)(vh + (size_t)rr * SEQ + s0 + sc8 * 8);
            }
        }

        // ---- S^T = K . Q^T + (-m)   (log2 units; Q pre-scaled)
        f32x16 SC[2];
        #pragma unroll
        for (int r = 0; r < 16; ++r) { SC[0][r] = -m; SC[1][r] = -m; }
        __builtin_amdgcn_s_setprio(1);
        #pragma unroll
        for (int ks = 0; ks < 4; ++ks) {
            const int chunk = 2 * ks + h;
            #pragma unroll
            for (int c = 0; c < 2; ++c) {
                const int row = c * 32 + q32;
                s16x8 kf = __builtin_bit_cast(s16x8, Kt[buf][chunk * 64 + (row ^ chunk)]);
                SC[c] = __builtin_amdgcn_mfma_f32_32x32x16_bf16(kf, qf[ks], SC[c], 0, 0, 0);
            }
        }
        __builtin_amdgcn_s_setprio(0);

        // ---- tile max via v_max3 tree, lane-local
        #define GETSC(i) ((i) < 16 ? SC[0][(i)] : SC[1][(i) - 16])
        float t0[11];
        #pragma unroll
        for (int r = 0; r < 10; ++r)
            t0[r] = max3f(GETSC(3 * r), GETSC(3 * r + 1), GETSC(3 * r + 2));
        t0[10] = fmaxf(GETSC(30), GETSC(31));
        float u0 = max3f(t0[0], t0[1], t0[2]);
        float u1 = max3f(t0[3], t0[4], t0[5]);
        float u2 = max3f(t0[6], t0[7], t0[8]);
        float u3 = fmaxf(t0[9], t0[10]);
        float rmb_l = fmaxf(max3f(u0, u1, u2), u3);
        float rmb = fmaxf(rmb_l, __shfl_xor(rmb_l, 32, 64));   // = tilemax - m
        #undef GETSC

        // defer-max (T13): rescale only if some row grew past m+8
        if (!__all(rmb <= 8.0f)) {
            const float delta = fmaxf(rmb, 0.f);
            const float fold = exp2_asm(-delta);
            lsum *= fold;
            O[0] *= fold;
            O[1] *= fold;
            m += delta;
            #pragma unroll
            for (int c = 0; c < 2; ++c)
                #pragma unroll
                for (int r = 0; r < 16; ++r)
                    SC[c][r] -= delta;
        }

        #pragma unroll
        for (int c = 0; c < 2; ++c)
            #pragma unroll
            for (int r = 0; r < 16; ++r)
                SC[c][r] = exp2_asm(SC[c][r]);

        // ---- row-sum on VALU (has slack; MFMA doesn't — R10 lesson)
        float s0a[8];
        #pragma unroll
        for (int r = 0; r < 8; ++r)
            s0a[r] = (SC[0][r] + SC[0][r + 8]) + (SC[1][r] + SC[1][r + 8]);
        #pragma unroll
        for (int d = 4; d; d >>= 1)
            #pragma unroll
            for (int r = 0; r < d; ++r) s0a[r] += s0a[r + d];
        lsum += s0a[0] + __shfl_xor(s0a[0], 32, 64);

        // ---- pack P^T fragments in-register (permlane32_swap: both words/swap)
        s16x8 pa[4];
        #pragma unroll
        for (int s = 0; s < 4; ++s) {
            const int c = s >> 1, rb = (s & 1) * 8;
            unsigned int a0 = cvtpk_bf16(SC[c][rb + 0], SC[c][rb + 1]);
            unsigned int a1 = cvtpk_bf16(SC[c][rb + 2], SC[c][rb + 3]);
            unsigned int b0 = cvtpk_bf16(SC[c][rb + 4], SC[c][rb + 5]);
            unsigned int b1 = cvtpk_bf16(SC[c][rb + 6], SC[c][rb + 7]);
            asm volatile("v_permlane32_swap_b32 %0, %1" : "+v"(a0), "+v"(b0));
            asm volatile("v_permlane32_swap_b32 %0, %1" : "+v"(a1), "+v"(b1));
            u32x4 wd;
            wd[0] = a0;   // [a0.lo | b0.lo]
            wd[1] = a1;   // [a1.lo | b1.lo]
            wd[2] = b0;   // [a0.hi | b0.hi]
            wd[3] = b1;   // [a1.hi | b1.hi]
            pa[s] = __builtin_bit_cast(s16x8, wd);
        }

        // ---- O^T += V^T . P^T
        __builtin_amdgcn_s_setprio(1);
        #pragma unroll
        for (int s = 0; s < 4; ++s) {
            const int chunk = 2 * s + h;
            #pragma unroll
            for (int c = 0; c < 2; ++c) {
                const int row = c * 32 + q32;
                s16x8 vf = __builtin_bit_cast(s16x8, Vt[buf][chunk * 64 + (row ^ chunk)]);
                O[c] = __builtin_amdgcn_mfma_f32_32x32x16_bf16(vf, pa[s], O[c], 0, 0, 0);
            }
        }
        __builtin_amdgcn_s_setprio(0);

        // ---- stage next tile into the other buffer; single barrier per tile
        if (kv < SEQ / 64 - 1) {
            #pragma unroll
            for (int p = 0; p < 2; ++p) {
                int rr = p * 32 + srow;
                Kt[buf ^ 1][sc8 * 64 + (rr ^ sc8)] = kreg[p];
                Vt[buf ^ 1][sc8 * 64 + (rr ^ sc8)] = vreg[p];
            }
            __syncthreads();
            buf ^= 1;
        }
    }

    // ---- epilogue: O^T[d][q]: d0 = 8*rq + 4*h + 32*c
    const float inv = 1.0f / lsum;
    const int b = bh >> 4, head = bh & 15;
    unsigned short* obase = aob + ((size_t)b * SEQ + qrow) * D_MODEL + head * DH;
    #pragma unroll
    for (int c = 0; c < 2; ++c) {
        #pragma unroll
        for (int rq = 0; rq < 4; ++rq) {
            const int d0 = 8 * rq + 4 * h + 32 * c;
            u16x4 pv;
            #pragma unroll
            for (int j = 0; j < 4; ++j) pv[j] = f2bf(O[c][rq * 4 + j] * inv);
            *(u16x4*)(obase + d0) = pv;
        }
    }
}

// ---------------------------------------------------------------------------
extern "C" void kernel_launch(void* const* d_in, const int* in_sizes, int n_in,
                              void* d_out, int out_size, void* d_ws, size_t ws_size,
                              hipStream_t stream)
{
    const float* Q  = (const float*)d_in[0];
    const float* K  = (const float*)d_in[1];
    const float* V  = (const float*)d_in[2];
    const float* Wq = (const float*)d_in[3];
    const float* bq = (const float*)d_in[4];
    const float* Wk = (const float*)d_in[5];
    const float* bk = (const float*)d_in[6];
    const float* Wv = (const float*)d_in[7];
    const float* bv = (const float*)d_in[8];
    const float* Wo = (const float*)d_in[9];
    const float* bo = (const float*)d_in[10];

    const size_t PER = (size_t)MROWS * D_MODEL;           // 8388608
    const size_t WSZ = (size_t)D_MODEL * D_MODEL;         // 1048576
    unsigned short* wqb = (unsigned short*)d_ws;
    unsigned short* wkb = wqb + WSZ;
    unsigned short* wvb = wkb + WSZ;
    unsigned short* wob = wvb + WSZ;
    unsigned short* qb2 = wob + WSZ;
    unsigned short* kb2 = qb2 + PER;
    unsigned short* vtb = kb2 + PER;
    unsigned short* aob = vtb + PER;

    dim3 gg(MROWS / 128, D_MODEL / 128);         // 64 x 8 = 512 blocks

    conv_w4<<<dim3(512, 4), 256, 0, stream>>>(Wq, Wk, Wv, Wo, wqb, wkb, wvb, wob);

    gemm_bt<1, true><<<gg, 256, 0, stream>>>(Q, wqb, bq, qb2, nullptr, QSCALE);
    gemm_bt<1, true><<<gg, 256, 0, stream>>>(K, wkb, bk, kb2, nullptr, 1.0f);
    gemm_bt<2, true><<<gg, 256, 0, stream>>>(V, wvb, bv, vtb, nullptr, 1.0f);

    flash_attn_mfma32<<<dim3(16 * BH), 256, 0, stream>>>(qb2, kb2, vtb, aob);

    gemm_bt<0, false><<<gg, 256, 0, stream>>>(aob, wob, bo, nullptr, (float*)d_out, 1.0f);
}

// Round 17
// 211.963 us; speedup vs baseline: 1.0237x; 1.0237x over previous
//
#include <hip/hip_runtime.h>
#include <math.h>

#define D_MODEL 1024
#define N_HEAD  16
#define DH      64
#define SEQ     2048
#define BATCH   4
#define BH      (BATCH*N_HEAD)   // 64
#define MROWS   (BATCH*SEQ)      // 8192

typedef __attribute__((ext_vector_type(8)))  short          s16x8;
typedef __attribute__((ext_vector_type(8)))  unsigned short u16x8;
typedef __attribute__((ext_vector_type(4)))  unsigned short u16x4;
typedef __attribute__((ext_vector_type(4)))  float          f32x4;
typedef __attribute__((ext_vector_type(16))) float          f32x16;
typedef __attribute__((ext_vector_type(4)))  unsigned int   u32x4;

#define QSCALE 0.18033688f   // 0.125 * log2(e)

typedef const __attribute__((address_space(1))) unsigned int gu32;
typedef __attribute__((address_space(3))) unsigned int lu32;
#define GLOAD_LDS16(g, l) __builtin_amdgcn_global_load_lds((gu32*)(g), (lu32*)(l), 16, 0, 0)

__device__ __forceinline__ unsigned short f2bf(float x) {
    unsigned int u = __float_as_uint(x);
    u += 0x7FFFu + ((u >> 16) & 1u);      // round-to-nearest-even
    return (unsigned short)(u >> 16);
}

__device__ __forceinline__ unsigned int cvtpk_bf16(float lo, float hi) {
    unsigned int r;
    asm("v_cvt_pk_bf16_f32 %0, %1, %2" : "=v"(r) : "v"(lo), "v"(hi));
    return r;
}

__device__ __forceinline__ float exp2_asm(float x) {
    float r;
    asm("v_exp_f32 %0, %1" : "=v"(r) : "v"(x));
    return r;
}

__device__ __forceinline__ float max3f(float a, float b, float c) {
    float r;
    asm("v_max3_f32 %0, %1, %2, %3" : "=v"(r) : "v"(a), "v"(b), "v"(c));
    return r;
}

// ---------------------------------------------------------------------------
// all four weight matrices fp32 -> bf16 in one dispatch. grid (512, 4).
// ---------------------------------------------------------------------------
__global__ __launch_bounds__(256) void conv_w4(const float* __restrict__ w0,
                                               const float* __restrict__ w1,
                                               const float* __restrict__ w2,
                                               const float* __restrict__ w3,
                                               unsigned short* __restrict__ o0,
                                               unsigned short* __restrict__ o1,
                                               unsigned short* __restrict__ o2,
                                               unsigned short* __restrict__ o3)
{
    const float* w; unsigned short* o;
    switch (blockIdx.y) {
        case 0:  w = w0; o = o0; break;
        case 1:  w = w1; o = o1; break;
        case 2:  w = w2; o = o2; break;
        default: w = w3; o = o3; break;
    }
    int i = blockIdx.x * 256 + threadIdx.x;
    const float4* p = (const float4*)w + (size_t)i * 2;
    float4 a = p[0], b = p[1];
    u16x8 v;
    v[0] = f2bf(a.x); v[1] = f2bf(a.y); v[2] = f2bf(a.z); v[3] = f2bf(a.w);
    v[4] = f2bf(b.x); v[5] = f2bf(b.y); v[6] = f2bf(b.z); v[7] = f2bf(b.w);
    *((u16x8*)o + i) = v;
}

// ---------------------------------------------------------------------------
// C[M=8192][N=1024] = A[M][1024] @ W(bf16)[N=1024][1024]^T + bias, then *oscale
// 128x128 tile, grid (64,8)=512 blocks (R12 measured-best dispatch shape).
// MACRO K-STEP = 128 as TWO 64-k sub-tiles per barrier pair (R15 measured
// best: halves barrier-drain count 16->8). R16's explicit dbuf stage-ahead
// was NEUTRAL-NEGATIVE (+5us) — m99/m100 confirmed: implicit wave-level
// overlap already captures the latency hiding; don't re-attempt.
// B staged via global_load_lds w/ pre-swizzled source; A reg-staged
// (fp32->bf16 cvtpk when AF32).
// ---------------------------------------------------------------------------
template<int MODE, bool AF32>
__global__ __launch_bounds__(256) void gemm_bt(const void* __restrict__ Av,
                                               const unsigned short* __restrict__ W,
                                               const float* __restrict__ bias,
                                               unsigned short* __restrict__ outb,
                                               float* __restrict__ outf,
                                               float oscale)
{
    __shared__ short As[2][128 * 64];   // 2 x 16KB sub-tiles, XOR-swizzled
    __shared__ short Bs[2][128 * 64];   // 2 x 16KB
    const int tid = threadIdx.x;
    const int w = tid >> 6, l = tid & 63;
    const int lr = l & 15, lg = l >> 4;
    const int wm = w >> 1, wn = w & 1;
    const int r0 = blockIdx.x * 128, c0 = blockIdx.y * 128;
    const int srow = tid >> 3;   // 0..31
    const int sc8  = tid & 7;    // 0..7

    f32x4 zz = {0.f, 0.f, 0.f, 0.f};
    f32x4 acc[4][4];
    #pragma unroll
    for (int i = 0; i < 4; ++i)
        #pragma unroll
        for (int j = 0; j < 4; ++j) acc[i][j] = zz;

    const unsigned short* Ab = (const unsigned short*)Av;
    const float*          Af = (const float*)Av;

    // per-lane pre-swizzled B source offsets (bytes), one per 8-row DMA
    const int lrow8 = l >> 3;      // 0..7
    const int lslot = l & 7;
    size_t bsrc[4];
    #pragma unroll
    for (int p = 0; p < 4; ++p)
        bsrc[p] = ((size_t)(c0 + w * 32 + p * 8 + lrow8) * 1024 + (size_t)((lslot ^ lrow8) * 8)) * 2;

    u16x8 ar[2][4];
    float4 arf[2][4][2];
    #pragma unroll
    for (int sub = 0; sub < 2; ++sub) {
        #pragma unroll
        for (int p = 0; p < 4; ++p) {
            int row = p * 32 + srow;
            if (AF32) {
                arf[sub][p][0] = *(const float4*)(Af + (size_t)(r0 + row) * 1024 + sub * 64 + sc8 * 8);
                arf[sub][p][1] = *(const float4*)(Af + (size_t)(r0 + row) * 1024 + sub * 64 + sc8 * 8 + 4);
            } else {
                ar[sub][p] = *(const u16x8*)(Ab + (size_t)(r0 + row) * 1024 + sub * 64 + sc8 * 8);
            }
        }
    }

    for (int ks = 0; ks < 8; ++ks) {   // 8 macro-steps of 128 k
        __syncthreads();   // all reads of As/Bs from previous step done
        #pragma unroll
        for (int sub = 0; sub < 2; ++sub)
            #pragma unroll
            for (int p = 0; p < 4; ++p)
                GLOAD_LDS16((const char*)W + bsrc[p] + (size_t)ks * 256 + sub * 128,
                            &Bs[sub][(w * 32 + p * 8) * 64]);
        #pragma unroll
        for (int sub = 0; sub < 2; ++sub) {
            #pragma unroll
            for (int p = 0; p < 4; ++p) {
                int row = p * 32 + srow;
                if (AF32) {
                    u32x4 wd;
                    wd[0] = cvtpk_bf16(arf[sub][p][0].x, arf[sub][p][0].y);
                    wd[1] = cvtpk_bf16(arf[sub][p][0].z, arf[sub][p][0].w);
                    wd[2] = cvtpk_bf16(arf[sub][p][1].x, arf[sub][p][1].y);
                    wd[3] = cvtpk_bf16(arf[sub][p][1].z, arf[sub][p][1].w);
                    *(u16x8*)&As[sub][row * 64 + ((sc8 ^ (row & 7)) * 8)] = __builtin_bit_cast(u16x8, wd);
                } else {
                    *(u16x8*)&As[sub][row * 64 + ((sc8 ^ (row & 7)) * 8)] = ar[sub][p];
                }
            }
        }
        __syncthreads();   // drains vmcnt (B DMA) + lgkm (A writes) — once per 128 k
        if (ks < 7) {
            int k0 = (ks + 1) * 128;
            #pragma unroll
            for (int sub = 0; sub < 2; ++sub) {
                #pragma unroll
                for (int p = 0; p < 4; ++p) {
                    int row = p * 32 + srow;
                    if (AF32) {
                        arf[sub][p][0] = *(const float4*)(Af + (size_t)(r0 + row) * 1024 + k0 + sub * 64 + sc8 * 8);
                        arf[sub][p][1] = *(const float4*)(Af + (size_t)(r0 + row) * 1024 + k0 + sub * 64 + sc8 * 8 + 4);
                    } else {
                        ar[sub][p] = *(const u16x8*)(Ab + (size_t)(r0 + row) * 1024 + k0 + sub * 64 + sc8 * 8);
                    }
                }
            }
        }
        #pragma unroll
        for (int sub = 0; sub < 2; ++sub) {
            #pragma unroll
            for (int t = 0; t < 2; ++t) {
                const int k8 = lg + 4 * t;
                s16x8 af[4], bw[4];
                #pragma unroll
                for (int i = 0; i < 4; ++i) {
                    int rowa = wm * 64 + i * 16 + lr;
                    af[i] = *(const s16x8*)&As[sub][rowa * 64 + ((k8 ^ (rowa & 7)) * 8)];
                    int rowb = wn * 64 + i * 16 + lr;
                    bw[i] = *(const s16x8*)&Bs[sub][rowb * 64 + ((k8 ^ (rowb & 7)) * 8)];
                }
                #pragma unroll
                for (int i = 0; i < 4; ++i)
                    #pragma unroll
                    for (int j = 0; j < 4; ++j)
                        acc[i][j] = __builtin_amdgcn_mfma_f32_16x16x32_bf16(af[i], bw[j], acc[i][j], 0, 0, 0);
            }
        }
    }

    #pragma unroll
    for (int i = 0; i < 4; ++i) {
        #pragma unroll
        for (int j = 0; j < 4; ++j) {
            const int colb = c0 + wn * 64 + j * 16 + lr;
            const float bv = bias[colb];
            if (MODE == 2) {
                const int row = r0 + wm * 64 + i * 16 + lg * 4;
                const int b = row >> 11, s = row & 2047;
                const int h = colb >> 6, d = colb & 63;
                u16x4 pv;
                pv[0] = f2bf((acc[i][j][0] + bv) * oscale);
                pv[1] = f2bf((acc[i][j][1] + bv) * oscale);
                pv[2] = f2bf((acc[i][j][2] + bv) * oscale);
                pv[3] = f2bf((acc[i][j][3] + bv) * oscale);
                *(u16x4*)(outb + ((size_t)(b * N_HEAD + h) * DH + d) * SEQ + s) = pv;
            } else {
                #pragma unroll
                for (int rg = 0; rg < 4; ++rg) {
                    const int row = r0 + wm * 64 + i * 16 + lg * 4 + rg;
                    const float v = acc[i][j][rg] + bv;
                    if (MODE == 0) {
                        outf[(size_t)row * D_MODEL + colb] = v;
                    } else {
                        const int b = row >> 11, s = row & 2047;
                        const int h = colb >> 6, d = colb & 63;
                        outb[((size_t)(b * N_HEAD + h) * SEQ + s) * DH + d] = f2bf(v * oscale);
                    }
                }
            }
        }
    }
}

// ---------------------------------------------------------------------------
// Swapped-operand MFMA flash attention (32x32x16), log2-domain, dbuf LDS.
// R12 version verbatim (measured 96.4us, FETCH 27.7MB). R13's max-free +
// ZERO-reg variant raised occupancy 33->43% and broke the fragile L2
// lockstep of same-head blocks (FETCH 27.7->711MB, 26x): per-XCD K/V
// working set is exactly 4MB=L2, so pacing changes cause thrash. Do not
// alter this kernel's timing/occupancy without checking FETCH_SIZE.
// ---------------------------------------------------------------------------
__global__ __launch_bounds__(256, 4) void flash_attn_mfma32(const unsigned short* __restrict__ qb,
                                                            const unsigned short* __restrict__ kb,
                                                            const unsigned short* __restrict__ vtb,
                                                            unsigned short* __restrict__ aob)
{
    __shared__ u16x8 Kt[2][512];   // 16KB double-buffered
    __shared__ u16x8 Vt[2][512];   // 16KB

    const int tid = threadIdx.x;
    const int w = tid >> 6, l = tid & 63;
    const int q32 = l & 31;
    const int h = l >> 5;

    // XCD-aware decode: all 16 q-tiles of a (b,h) land on one XCD
    const int wg   = blockIdx.x;          // 0..1023
    const int xcd  = wg & 7;
    const int slot = wg >> 3;             // 0..127
    const int bh   = xcd * 8 + (slot >> 4);
    const int qt   = slot & 15;

    const unsigned short* qh = qb + (size_t)bh * SEQ * DH;
    const unsigned short* kh = kb + (size_t)bh * SEQ * DH;
    const unsigned short* vh = vtb + (size_t)bh * DH * SEQ;

    const int qrow = qt * 128 + w * 32 + q32;

    s16x8 qf[4];
    #pragma unroll
    for (int ks = 0; ks < 4; ++ks)
        qf[ks] = *(const s16x8*)(qh + (size_t)qrow * DH + ks * 16 + h * 8);

    f32x16 O[2];
    #pragma unroll
    for (int r = 0; r < 16; ++r) { O[0][r] = 0.f; O[1][r] = 0.f; }
    float m = 0.f, lsum = 0.f;   // log2-domain; P bounded by 2^8 via defer check

    const int srow = tid >> 3;   // 0..31
    const int sc8  = tid & 7;

    u16x8 kreg[2], vreg[2];
    #pragma unroll
    for (int p = 0; p < 2; ++p) {
        int rr = p * 32 + srow;
        kreg[p] = *(const u16x8*)(kh + (size_t)rr * DH + sc8 * 8);
        vreg[p] = *(const u16x8*)(vh + (size_t)rr * SEQ + sc8 * 8);
    }
    #pragma unroll
    for (int p = 0; p < 2; ++p) {
        int rr = p * 32 + srow;
        Kt[0][sc8 * 64 + (rr ^ sc8)] = kreg[p];
        Vt[0][sc8 * 64 + (rr ^ sc8)] = vreg[p];
    }
    __syncthreads();

    int buf = 0;
    for (int kv = 0; kv < SEQ / 64; ++kv) {
        // issue next tile's global loads early (latency hides under compute)
        if (kv < SEQ / 64 - 1) {
            const int s0 = (kv + 1) * 64;
            #pragma unroll
            for (int p = 0; p < 2; ++p) {
                int rr = p * 32 + srow;
                kreg[p] = *(const u16x8*)(kh + (size_t)(s0 + rr) * DH + sc8 * 8);
                vreg[p] = *(const u16x8*)(vh + (size_t)rr * SEQ + s0 + sc8 * 8);
            }
        }

        // ---- S^T = K . Q^T + (-m)   (log2 units; Q pre-scaled)
        f32x16 SC[2];
        #pragma unroll
        for (int r = 0; r < 16; ++r) { SC[0][r] = -m; SC[1][r] = -m; }
        __builtin_amdgcn_s_setprio(1);
        #pragma unroll
        for (int ks = 0; ks < 4; ++ks) {
            const int chunk = 2 * ks + h;
            #pragma unroll
            for (int c = 0; c < 2; ++c) {
                const int row = c * 32 + q32;
                s16x8 kf = __builtin_bit_cast(s16x8, Kt[buf][chunk * 64 + (row ^ chunk)]);
                SC[c] = __builtin_amdgcn_mfma_f32_32x32x16_bf16(kf, qf[ks], SC[c], 0, 0, 0);
            }
        }
        __builtin_amdgcn_s_setprio(0);

        // ---- tile max via v_max3 tree, lane-local
        #define GETSC(i) ((i) < 16 ? SC[0][(i)] : SC[1][(i) - 16])
        float t0[11];
        #pragma unroll
        for (int r = 0; r < 10; ++r)
            t0[r] = max3f(GETSC(3 * r), GETSC(3 * r + 1), GETSC(3 * r + 2));
        t0[10] = fmaxf(GETSC(30), GETSC(31));
        float u0 = max3f(t0[0], t0[1], t0[2]);
        float u1 = max3f(t0[3], t0[4], t0[5]);
        float u2 = max3f(t0[6], t0[7], t0[8]);
        float u3 = fmaxf(t0[9], t0[10]);
        float rmb_l = fmaxf(max3f(u0, u1, u2), u3);
        float rmb = fmaxf(rmb_l, __shfl_xor(rmb_l, 32, 64));   // = tilemax - m
        #undef GETSC

        // defer-max (T13): rescale only if some row grew past m+8
        if (!__all(rmb <= 8.0f)) {
            const float delta = fmaxf(rmb, 0.f);
            const float fold = exp2_asm(-delta);
            lsum *= fold;
            O[0] *= fold;
            O[1] *= fold;
            m += delta;
            #pragma unroll
            for (int c = 0; c < 2; ++c)
                #pragma unroll
                for (int r = 0; r < 16; ++r)
                    SC[c][r] -= delta;
        }

        #pragma unroll
        for (int c = 0; c < 2; ++c)
            #pragma unroll
            for (int r = 0; r < 16; ++r)
                SC[c][r] = exp2_asm(SC[c][r]);

        // ---- row-sum on VALU (has slack; MFMA doesn't — R10 lesson)
        float s0a[8];
        #pragma unroll
        for (int r = 0; r < 8; ++r)
            s0a[r] = (SC[0][r] + SC[0][r + 8]) + (SC[1][r] + SC[1][r + 8]);
        #pragma unroll
        for (int d = 4; d; d >>= 1)
            #pragma unroll
            for (int r = 0; r < d; ++r) s0a[r] += s0a[r + d];
        lsum += s0a[0] + __shfl_xor(s0a[0], 32, 64);

        // ---- pack P^T fragments in-register (permlane32_swap: both words/swap)
        s16x8 pa[4];
        #pragma unroll
        for (int s = 0; s < 4; ++s) {
            const int c = s >> 1, rb = (s & 1) * 8;
            unsigned int a0 = cvtpk_bf16(SC[c][rb + 0], SC[c][rb + 1]);
            unsigned int a1 = cvtpk_bf16(SC[c][rb + 2], SC[c][rb + 3]);
            unsigned int b0 = cvtpk_bf16(SC[c][rb + 4], SC[c][rb + 5]);
            unsigned int b1 = cvtpk_bf16(SC[c][rb + 6], SC[c][rb + 7]);
            asm volatile("v_permlane32_swap_b32 %0, %1" : "+v"(a0), "+v"(b0));
            asm volatile("v_permlane32_swap_b32 %0, %1" : "+v"(a1), "+v"(b1));
            u32x4 wd;
            wd[0] = a0;   // [a0.lo | b0.lo]
            wd[1] = a1;   // [a1.lo | b1.lo]
            wd[2] = b0;   // [a0.hi | b0.hi]
            wd[3] = b1;   // [a1.hi | b1.hi]
            pa[s] = __builtin_bit_cast(s16x8, wd);
        }

        // ---- O^T += V^T . P^T
        __builtin_amdgcn_s_setprio(1);
        #pragma unroll
        for (int s = 0; s < 4; ++s) {
            const int chunk = 2 * s + h;
            #pragma unroll
            for (int c = 0; c < 2; ++c) {
                const int row = c * 32 + q32;
                s16x8 vf = __builtin_bit_cast(s16x8, Vt[buf][chunk * 64 + (row ^ chunk)]);
                O[c] = __builtin_amdgcn_mfma_f32_32x32x16_bf16(vf, pa[s], O[c], 0, 0, 0);
            }
        }
        __builtin_amdgcn_s_setprio(0);

        // ---- stage next tile into the other buffer; single barrier per tile
        if (kv < SEQ / 64 - 1) {
            #pragma unroll
            for (int p = 0; p < 2; ++p) {
                int rr = p * 32 + srow;
                Kt[buf ^ 1][sc8 * 64 + (rr ^ sc8)] = kreg[p];
                Vt[buf ^ 1][sc8 * 64 + (rr ^ sc8)] = vreg[p];
            }
            __syncthreads();
            buf ^= 1;
        }
    }

    // ---- epilogue: O^T[d][q]: d0 = 8*rq + 4*h + 32*c
    const float inv = 1.0f / lsum;
    const int b = bh >> 4, head = bh & 15;
    unsigned short* obase = aob + ((size_t)b * SEQ + qrow) * D_MODEL + head * DH;
    #pragma unroll
    for (int c = 0; c < 2; ++c) {
        #pragma unroll
        for (int rq = 0; rq < 4; ++rq) {
            const int d0 = 8 * rq + 4 * h + 32 * c;
            u16x4 pv;
            #pragma unroll
            for (int j = 0; j < 4; ++j) pv[j] = f2bf(O[c][rq * 4 + j] * inv);
            *(u16x4*)(obase + d0) = pv;
        }
    }
}

// ---------------------------------------------------------------------------
extern "C" void kernel_launch(void* const* d_in, const int* in_sizes, int n_in,
                              void* d_out, int out_size, void* d_ws, size_t ws_size,
                              hipStream_t stream)
{
    const float* Q  = (const float*)d_in[0];
    const float* K  = (const float*)d_in[1];
    const float* V  = (const float*)d_in[2];
    const float* Wq = (const float*)d_in[3];
    const float* bq = (const float*)d_in[4];
    const float* Wk = (const float*)d_in[5];
    const float* bk = (const float*)d_in[6];
    const float* Wv = (const float*)d_in[7];
    const float* bv = (const float*)d_in[8];
    const float* Wo = (const float*)d_in[9];
    const float* bo = (const float*)d_in[10];

    const size_t PER = (size_t)MROWS * D_MODEL;           // 8388608
    const size_t WSZ = (size_t)D_MODEL * D_MODEL;         // 1048576
    unsigned short* wqb = (unsigned short*)d_ws;
    unsigned short* wkb = wqb + WSZ;
    unsigned short* wvb = wkb + WSZ;
    unsigned short* wob = wvb + WSZ;
    unsigned short* qb2 = wob + WSZ;
    unsigned short* kb2 = qb2 + PER;
    unsigned short* vtb = kb2 + PER;
    unsigned short* aob = vtb + PER;

    dim3 gg(MROWS / 128, D_MODEL / 128);         // 64 x 8 = 512 blocks

    conv_w4<<<dim3(512, 4), 256, 0, stream>>>(Wq, Wk, Wv, Wo, wqb, wkb, wvb, wob);

    gemm_bt<1, true><<<gg, 256, 0, stream>>>(Q, wqb, bq, qb2, nullptr, QSCALE);
    gemm_bt<1, true><<<gg, 256, 0, stream>>>(K, wkb, bk, kb2, nullptr, 1.0f);
    gemm_bt<2, true><<<gg, 256, 0, stream>>>(V, wvb, bv, vtb, nullptr, 1.0f);

    flash_attn_mfma32<<<dim3(16 * BH), 256, 0, stream>>>(qb2, kb2, vtb, aob);

    gemm_bt<0, false><<<gg, 256, 0, stream>>>(aob, wob, bo, nullptr, (float*)d_out, 1.0f);
}